// Round 1
// baseline (418.116 us; speedup 1.0000x reference)
//
#include <hip/hip_runtime.h>

#define L 1024
#define LM1 1023
#define NB 32

// ---------------- Kernel 1: per-batch lens + scale, zero the output ----------
__global__ void prep_kernel(const int* __restrict__ mask,
                            float* __restrict__ scale,   // ws: 32 floats
                            int* __restrict__ lens_out,  // ws: 32 ints
                            float* __restrict__ out) {
    const int b = blockIdx.x;        // 0..31
    const int t = threadIdx.x;       // 256 threads
    const int* mrow = mask + b * L;
    int s = 0;
    for (int j = t; j < L; j += 256) s += mrow[j];
    // wave (64-lane) reduce
    for (int off = 32; off > 0; off >>= 1) s += __shfl_down(s, off, 64);
    __shared__ int wsum[4];
    if ((t & 63) == 0) wsum[t >> 6] = s;
    __syncthreads();
    if (t == 0) {
        const int total = wsum[0] + wsum[1] + wsum[2] + wsum[3];
        const int lens = total - 2;
        lens_out[b] = lens;
        float sc = 0.0f;
        if (lens > 0) {
            const float d = (float)lens * (float)lens;  // >= 1 when lens > 0
            sc = 1.0f / (32.0f * d);
        }
        scale[b] = sc;
        if (b == 0) out[0] = 0.0f;   // harness poisons d_out; kernel2 atomics run after this kernel completes
    }
}

// ---------------- Kernel 2: masked |T - A^2| row sums ------------------------
__global__ void __launch_bounds__(256)
loss_kernel(const float* __restrict__ input,
            const float* __restrict__ target,
            const float* __restrict__ scale,
            const int* __restrict__ lens,
            float* __restrict__ out) {
    const int i = blockIdx.x;        // row 0..1022
    const int b = blockIdx.y;        // batch
    const int len = lens[b];
    if (i >= len) return;            // whole block idle past the masked region

    const float sc = scale[b];
    const size_t slab = (size_t)b * L * L;
    const float* trow = target + slab + (size_t)i * L;          // T[b,i,0]
    const float* irow = input  + slab + (size_t)(i + 1) * L + 1; // input[b,i+1,1]

    const int t = threadIdx.x;
    float acc = 0.0f;
    const int j = t * 4;             // covers 0..1023 >= len (<=1022)
    if (j < len) {
        // target: row base 4KB-aligned, j%4==0 -> 16B-aligned float4
        const float4 tv = *reinterpret_cast<const float4*>(trow + j);
        // input: +1 column offset, use scalar dword loads (4B-aligned)
        const float a0 = irow[j + 0];
        const float a1 = irow[j + 1];
        const float a2 = irow[j + 2];
        const float a3 = irow[j + 3];
        if (j + 3 < len) {
            acc = fabsf(tv.x - a0 * a0) + fabsf(tv.y - a1 * a1)
                + fabsf(tv.z - a2 * a2) + fabsf(tv.w - a3 * a3);
        } else {
            const float tvv[4] = {tv.x, tv.y, tv.z, tv.w};
            const float avv[4] = {a0, a1, a2, a3};
            for (int k = 0; k < 4; ++k)
                if (j + k < len) acc += fabsf(tvv[k] - avv[k] * avv[k]);
        }
    }

    // block reduce: wave shfl then LDS
    for (int off = 32; off > 0; off >>= 1) acc += __shfl_down(acc, off, 64);
    __shared__ float wsum[4];
    if ((t & 63) == 0) wsum[t >> 6] = acc;
    __syncthreads();
    if (t == 0) {
        const float s = wsum[0] + wsum[1] + wsum[2] + wsum[3];
        atomicAdd(out, s * sc);
    }
}

extern "C" void kernel_launch(void* const* d_in, const int* in_sizes, int n_in,
                              void* d_out, int out_size, void* d_ws, size_t ws_size,
                              hipStream_t stream) {
    const float* input  = (const float*)d_in[0];   // (32,1024,1024) f32
    const int*   mask   = (const int*)d_in[1];     // (32,1024) i32
    const float* target = (const float*)d_in[2];   // (32,1024,1024) f32
    float* out = (float*)d_out;

    float* scale = (float*)d_ws;                   // 32 floats
    int*   lens  = (int*)((char*)d_ws + 32 * sizeof(float));

    prep_kernel<<<dim3(NB), dim3(256), 0, stream>>>(mask, scale, lens, out);
    loss_kernel<<<dim3(LM1, NB), dim3(256), 0, stream>>>(input, target, scale, lens, out);
}

// Round 3
// 249.845 us; speedup vs baseline: 1.6735x; 1.6735x over previous
//
#include <hip/hip_runtime.h>

#define L 1024
#define NB 32
#define ROWS 8                         // rows per block
#define NCHUNK 128                     // ceil(1023 / ROWS)

// ---------------- Kernel 1: per-batch lens + scale ---------------------------
__global__ void prep_kernel(const int* __restrict__ mask,
                            float* __restrict__ scale,   // ws: 32 floats
                            int* __restrict__ lens_out) {// ws: 32 ints
    const int b = blockIdx.x;        // 0..31
    const int t = threadIdx.x;       // 256 threads
    const int* mrow = mask + b * L;
    int s = 0;
    for (int j = t; j < L; j += 256) s += mrow[j];
    for (int off = 32; off > 0; off >>= 1) s += __shfl_down(s, off, 64);
    __shared__ int wsum[4];
    if ((t & 63) == 0) wsum[t >> 6] = s;
    __syncthreads();
    if (t == 0) {
        const int total = wsum[0] + wsum[1] + wsum[2] + wsum[3];
        const int lens = total - 2;
        lens_out[b] = lens;
        float sc = 0.0f;
        if (lens > 0) {
            const float d = (float)lens * (float)lens;
            sc = 1.0f / (32.0f * d);
        }
        scale[b] = sc;
    }
}

// ---------------- Kernel 2: masked |T - A^2| partial sums --------------------
__global__ void __launch_bounds__(256)
loss_kernel(const float* __restrict__ input,
            const float* __restrict__ target,
            const float* __restrict__ scale,
            const int* __restrict__ lens,
            float* __restrict__ partials) {  // ws: NB*NCHUNK floats
    const int b = blockIdx.x;        // batch
    const int chunk = blockIdx.y;    // row chunk
    const int len = lens[b];
    const int row0 = chunk * ROWS;
    const int t = threadIdx.x;

    float acc = 0.0f;
    if (row0 < len) {
        const int rend = min(row0 + ROWS, len);
        const size_t slab = (size_t)b * L * L;
        for (int i = row0; i < rend; ++i) {
            const float* trow = target + slab + (size_t)i * L;           // T[b,i,0]
            const float* irow = input  + slab + (size_t)(i + 1) * L + 1; // input[b,i+1,1]
            for (int j = t * 4; j < len; j += 1024) {
                const float4 tv = *reinterpret_cast<const float4*>(trow + j);
                const float a0 = irow[j + 0];
                const float a1 = irow[j + 1];
                const float a2 = irow[j + 2];
                const float a3 = irow[j + 3];
                if (j + 3 < len) {
                    acc += fabsf(tv.x - a0 * a0) + fabsf(tv.y - a1 * a1)
                         + fabsf(tv.z - a2 * a2) + fabsf(tv.w - a3 * a3);
                } else {
                    const float tvv[4] = {tv.x, tv.y, tv.z, tv.w};
                    const float avv[4] = {a0, a1, a2, a3};
                    for (int k = 0; k < 4; ++k)
                        if (j + k < len) acc += fabsf(tvv[k] - avv[k] * avv[k]);
                }
            }
        }
    }

    // block reduce: wave shfl then LDS
    for (int off = 32; off > 0; off >>= 1) acc += __shfl_down(acc, off, 64);
    __shared__ float wsum[4];
    if ((t & 63) == 0) wsum[t >> 6] = acc;
    __syncthreads();
    if (t == 0) {
        const float s = wsum[0] + wsum[1] + wsum[2] + wsum[3];
        // ALWAYS write (d_ws is re-poisoned before every timed launch)
        partials[b * NCHUNK + chunk] = s * scale[b];
    }
}

// ---------------- Kernel 3: final sum of partials ----------------------------
__global__ void __launch_bounds__(256)
reduce_kernel(const float* __restrict__ partials, float* __restrict__ out) {
    const int t = threadIdx.x;
    float s = 0.0f;
    for (int k = t; k < NB * NCHUNK; k += 256) s += partials[k];
    for (int off = 32; off > 0; off >>= 1) s += __shfl_down(s, off, 64);
    __shared__ float wsum[4];
    if ((t & 63) == 0) wsum[t >> 6] = s;
    __syncthreads();
    if (t == 0) out[0] = wsum[0] + wsum[1] + wsum[2] + wsum[3];
}

extern "C" void kernel_launch(void* const* d_in, const int* in_sizes, int n_in,
                              void* d_out, int out_size, void* d_ws, size_t ws_size,
                              hipStream_t stream) {
    const float* input  = (const float*)d_in[0];   // (32,1024,1024) f32
    const int*   mask   = (const int*)d_in[1];     // (32,1024) i32
    const float* target = (const float*)d_in[2];   // (32,1024,1024) f32
    float* out = (float*)d_out;

    float* scale    = (float*)d_ws;                            // 32 floats
    int*   lens     = (int*)((char*)d_ws + 32 * sizeof(float)); // 32 ints
    float* partials = (float*)((char*)d_ws + 64 * sizeof(float)); // NB*NCHUNK floats

    prep_kernel<<<dim3(NB), dim3(256), 0, stream>>>(mask, scale, lens);
    loss_kernel<<<dim3(NB, NCHUNK), dim3(256), 0, stream>>>(input, target, scale, lens, partials);
    reduce_kernel<<<dim3(1), dim3(256), 0, stream>>>(partials, out);
}